// Round 8
// baseline (87.148 us; speedup 1.0000x reference)
//
#include <hip/hip_runtime.h>
#include <math.h>

// pred [65536, 1024] f32, target [65536] int32
static constexpr int N = 65536;
static constexpr int C = 1024;
static constexpr float EPS = 1e-9f;

// Math (validated absmax==0.0 in R4..R7):
//   total = termA + sum_t (log2e*x_t - log2(S[c_t]))
//   termA = -log2e * C * (1 + N*EPS)       (analytic: softmax cols sum to 1)
//   loss  = -total / (N*C)
//
// ws float layout (no pre-zeroing dispatch; no atomic accumulators):
//   [0..1023]    logS[C]        written by epilogue phase A (agent-release)
//   [1024,1025]  counters[2]    zeroed by K1 block 0
//   [1088..1343] gArr[256]      per-block partial contributions (phase B)
//   [4096..]     partial[RB][C] per-rowblock column partials (K1)

// ---------------------------------------------------------------------------
// K1: streaming column partials of exp, software-pipelined.
// Thread t owns columns 4t..4t+3; block covers RPB consecutive rows.
// Each iteration issues the NEXT batch's 8 float4 loads, then consumes the
// current batch strictly in load order (per-register vmcnt, queue never
// drains). __launch_bounds__(256,4) caps VGPR at 128 so 4 blocks/CU are
// GUARANTEED resident -> grid of 1024 runs in ONE round, no scheduling tail
// (the R7 2048-block config ran 1536+512 = two rounds, ~1.25x stretch).
template <int RPB>
__global__ __launch_bounds__(256, 4) void colsum_kernel(
    const float* __restrict__ pred, float* __restrict__ partial,
    int* __restrict__ counters) {
    const int tid = threadIdx.x;                   // 0..255
    if (blockIdx.x == 0 && tid == 0) { counters[0] = 0; counters[1] = 0; }

    const float4* __restrict__ p4 =
        reinterpret_cast<const float4*>(pred) +
        (size_t)blockIdx.x * RPB * (C / 4) + tid;

    float a0 = 0.f, a1 = 0.f, a2 = 0.f, a3 = 0.f;

    // prologue: batch 0 in flight
    float4 v0 = p4[0 * (C / 4)];
    float4 v1 = p4[1 * (C / 4)];
    float4 v2 = p4[2 * (C / 4)];
    float4 v3 = p4[3 * (C / 4)];
    float4 v4 = p4[4 * (C / 4)];
    float4 v5 = p4[5 * (C / 4)];
    float4 v6 = p4[6 * (C / 4)];
    float4 v7 = p4[7 * (C / 4)];
    p4 += 8 * (C / 4);

#pragma unroll 1
    for (int b = 0; b < RPB / 8 - 1; ++b) {
        float4 w0 = p4[0 * (C / 4)];
        float4 w1 = p4[1 * (C / 4)];
        float4 w2 = p4[2 * (C / 4)];
        float4 w3 = p4[3 * (C / 4)];
        float4 w4 = p4[4 * (C / 4)];
        float4 w5 = p4[5 * (C / 4)];
        float4 w6 = p4[6 * (C / 4)];
        float4 w7 = p4[7 * (C / 4)];
        p4 += 8 * (C / 4);
        __builtin_amdgcn_sched_barrier(0);   // keep the 8 issues above the math

        a0 += __expf(v0.x); a1 += __expf(v0.y); a2 += __expf(v0.z); a3 += __expf(v0.w);
        a0 += __expf(v1.x); a1 += __expf(v1.y); a2 += __expf(v1.z); a3 += __expf(v1.w);
        a0 += __expf(v2.x); a1 += __expf(v2.y); a2 += __expf(v2.z); a3 += __expf(v2.w);
        a0 += __expf(v3.x); a1 += __expf(v3.y); a2 += __expf(v3.z); a3 += __expf(v3.w);
        a0 += __expf(v4.x); a1 += __expf(v4.y); a2 += __expf(v4.z); a3 += __expf(v4.w);
        a0 += __expf(v5.x); a1 += __expf(v5.y); a2 += __expf(v5.z); a3 += __expf(v5.w);
        a0 += __expf(v6.x); a1 += __expf(v6.y); a2 += __expf(v6.z); a3 += __expf(v6.w);
        a0 += __expf(v7.x); a1 += __expf(v7.y); a2 += __expf(v7.z); a3 += __expf(v7.w);

        v0 = w0; v1 = w1; v2 = w2; v3 = w3;
        v4 = w4; v5 = w5; v6 = w6; v7 = w7;
    }
    a0 += __expf(v0.x); a1 += __expf(v0.y); a2 += __expf(v0.z); a3 += __expf(v0.w);
    a0 += __expf(v1.x); a1 += __expf(v1.y); a2 += __expf(v1.z); a3 += __expf(v1.w);
    a0 += __expf(v2.x); a1 += __expf(v2.y); a2 += __expf(v2.z); a3 += __expf(v2.w);
    a0 += __expf(v3.x); a1 += __expf(v3.y); a2 += __expf(v3.z); a3 += __expf(v3.w);
    a0 += __expf(v4.x); a1 += __expf(v4.y); a2 += __expf(v4.z); a3 += __expf(v4.w);
    a0 += __expf(v5.x); a1 += __expf(v5.y); a2 += __expf(v5.z); a3 += __expf(v5.w);
    a0 += __expf(v6.x); a1 += __expf(v6.y); a2 += __expf(v6.z); a3 += __expf(v6.w);
    a0 += __expf(v7.x); a1 += __expf(v7.y); a2 += __expf(v7.z); a3 += __expf(v7.w);

    reinterpret_cast<float4*>(partial + (size_t)blockIdx.x * C)[tid] =
        make_float4(a0, a1, a2, a3);
}

// ---------------------------------------------------------------------------
// Epilogue (single kernel, 256 blocks x 256 threads, all co-resident):
//  phase A (blocks 0..63): reduce RB partials -> logS for 16 owned columns
//    (R6-validated access: wave reads 8 rows x 64 B full lines, 8 streams).
//    agent-release stores + arrival on counters[0].
//  all blocks spin-acquire until counters[0]==64.
//  phase B: one target per thread: coalesced tgt read, scattered pred dword,
//    logS via agent-scope load (fresh across XCDs). Block reduce -> gArr,
//    arrival on counters[1]; last block sums gArr[256], finalizes in double.
__global__ __launch_bounds__(256) void epilogue_kernel(
    const float* __restrict__ partial, const int* __restrict__ tgt,
    const float* __restrict__ pred, float* __restrict__ logS,
    int* __restrict__ counters, float* __restrict__ gArr,
    float* __restrict__ out, int RB) {
    const int t = threadIdx.x;

    if (blockIdx.x < 64) {
        const int cp = t & 7;
        const int r0 = t >> 3;
        const int c0 = blockIdx.x * 16;
        const int eighth = RB / 8;

        const float2* __restrict__ p2 =
            reinterpret_cast<const float2*>(partial) + (c0 >> 1) + cp;

        float2 a[8];
#pragma unroll
        for (int j = 0; j < 8; ++j) a[j] = make_float2(0.f, 0.f);
        for (int r = r0; r < eighth; r += 32) {
#pragma unroll
            for (int j = 0; j < 8; ++j) {
                const float2 v = p2[(size_t)(r + j * eighth) * (C / 2)];
                a[j].x += v.x;
                a[j].y += v.y;
            }
        }
        float2 s;
        s.x = ((a[0].x + a[1].x) + (a[2].x + a[3].x)) + ((a[4].x + a[5].x) + (a[6].x + a[7].x));
        s.y = ((a[0].y + a[1].y) + (a[2].y + a[3].y)) + ((a[4].y + a[5].y) + (a[6].y + a[7].y));
#pragma unroll
        for (int off = 8; off <= 32; off <<= 1) {
            s.x += __shfl_xor(s.x, off, 64);
            s.y += __shfl_xor(s.y, off, 64);
        }
        __shared__ float2 wred[4][8];
        if ((t & 63) < 8) wred[t >> 6][cp] = s;
        __syncthreads();
        if (t < 8) {
            const float vx = wred[0][t].x + wred[1][t].x + wred[2][t].x + wred[3][t].x;
            const float vy = wred[0][t].y + wred[1][t].y + wred[2][t].y + wred[3][t].y;
            __hip_atomic_store(&logS[c0 + 2 * t],     log2f(vx),
                               __ATOMIC_RELEASE, __HIP_MEMORY_SCOPE_AGENT);
            __hip_atomic_store(&logS[c0 + 2 * t + 1], log2f(vy),
                               __ATOMIC_RELEASE, __HIP_MEMORY_SCOPE_AGENT);
        }
        __syncthreads();
        if (t == 0) {
            __threadfence();
            __hip_atomic_fetch_add(&counters[0], 1, __ATOMIC_ACQ_REL,
                                   __HIP_MEMORY_SCOPE_AGENT);
        }
    }

    // wait for all 64 phase-A blocks (256 blocks <= capacity: no deadlock)
    if (t == 0) {
        while (__hip_atomic_load(&counters[0], __ATOMIC_ACQUIRE,
                                 __HIP_MEMORY_SCOPE_AGENT) < 64)
            __builtin_amdgcn_s_sleep(2);
    }
    __syncthreads();

    // phase B: one target per thread
    const int n = blockIdx.x * 256 + t;
    const int c = tgt[n];
    const float x = pred[((size_t)n << 10) + c];      // C == 1024
    const float ls = __hip_atomic_load(&logS[c], __ATOMIC_RELAXED,
                                       __HIP_MEMORY_SCOPE_AGENT);
    float v = 1.4426950408889634f * x - ls;
#pragma unroll
    for (int off = 32; off > 0; off >>= 1)
        v += __shfl_down(v, off, 64);
    __shared__ float wsum[4];
    if ((t & 63) == 0) wsum[t >> 6] = v;
    __syncthreads();

    __shared__ int last;
    if (t == 0) {
        gArr[blockIdx.x] = wsum[0] + wsum[1] + wsum[2] + wsum[3];
        __threadfence();
        const int old = __hip_atomic_fetch_add(&counters[1], 1, __ATOMIC_ACQ_REL,
                                               __HIP_MEMORY_SCOPE_AGENT);
        last = (old == (int)gridDim.x - 1) ? 1 : 0;
    }
    __syncthreads();
    if (!last) return;

    float gl = __hip_atomic_load(&gArr[t], __ATOMIC_RELAXED,
                                 __HIP_MEMORY_SCOPE_AGENT);
#pragma unroll
    for (int off = 32; off > 0; off >>= 1)
        gl += __shfl_down(gl, off, 64);
    __shared__ float r1[4];
    if ((t & 63) == 0) r1[t >> 6] = gl;
    __syncthreads();
    if (t == 0) {
        const double LOG2E = 1.4426950408889634;
        const double SumContrib = (double)(r1[0] + r1[1] + r1[2] + r1[3]);
        const double termA = -LOG2E * (double)C * (1.0 + (double)N * (double)EPS);
        const double total = termA + SumContrib;
        out[0] = (float)(-total / ((double)N * (double)C));
    }
}

extern "C" void kernel_launch(void* const* d_in, const int* in_sizes, int n_in,
                              void* d_out, int out_size, void* d_ws, size_t ws_size,
                              hipStream_t stream) {
    const float* pred = (const float*)d_in[0];
    const int*   tgt  = (const int*)d_in[1];
    float* wsf      = (float*)d_ws;
    float* logS     = wsf;
    int*   counters = (int*)(wsf + 1024);
    float* gArr     = wsf + 1088;              // 256 entries
    float* partial  = wsf + 4096;              // 16 KB offset, 16B-aligned
    const size_t base_bytes = 4096 * sizeof(float);

    int RB = 1024;                              // 4 MB partials
    if (base_bytes + (size_t)RB * C * sizeof(float) > ws_size) RB = 512;

    if (RB == 1024)
        colsum_kernel<64><<<1024, 256, 0, stream>>>(pred, partial, counters);
    else
        colsum_kernel<128><<<512, 256, 0, stream>>>(pred, partial, counters);

    epilogue_kernel<<<256, 256, 0, stream>>>(partial, tgt, pred, logS,
                                             counters, gArr, (float*)d_out, RB);
}

// Round 9
// 63.128 us; speedup vs baseline: 1.3805x; 1.3805x over previous
//
#include <hip/hip_runtime.h>
#include <math.h>

// pred [65536, 1024] f32, target [65536] int32
static constexpr int N = 65536;
static constexpr int C = 1024;
static constexpr float EPS = 1e-9f;

// Math (validated absmax==0.0 in R4..R8):
//   total = termA + sum_t (log2e*x_t - log2(S[c_t]))
//   termA = -log2e * C * (1 + N*EPS)       (analytic: softmax cols sum to 1)
//   loss  = -total / (N*C)
//
// ws float layout (no pre-zeroing dispatch; no atomic accumulators):
//   [0..1023]   logS[C]        written by K2 (plain owned-column stores)
//   [1024]      counter        zeroed by K1 block 0; K3 arrival counter
//   [1088..1343] gArr[256]     per-block partial contributions (K3)
//   [4096..]    partial[RB][C] per-rowblock column partials (K1)

// ---------------------------------------------------------------------------
// K1: streaming column partials of exp, DEPTH-4 software pipeline.
// Thread t owns columns 4t..4t+3; block covers RPB consecutive rows.
// Rationale (R9): depth-8 needed ~84 VGPR -> 16 waves/CU; depth-4 fits under
// the 64-VGPR occupancy step -> 32 waves/CU (launch_bounds(256,8) pins it),
// grid 2048 = one full round. 4 loads in flight per wave x 2x waves beats
// 8-deep x half the waves for latency hiding (fill-kernel shape).
template <int RPB>
__global__ __launch_bounds__(256, 8) void colsum_kernel(
    const float* __restrict__ pred, float* __restrict__ partial,
    int* __restrict__ counter) {
    const int tid = threadIdx.x;                   // 0..255
    if (blockIdx.x == 0 && tid == 0) *counter = 0; // for K3's arrival counter

    const float4* __restrict__ p4 =
        reinterpret_cast<const float4*>(pred) +
        (size_t)blockIdx.x * RPB * (C / 4) + tid;

    float a0 = 0.f, a1 = 0.f, a2 = 0.f, a3 = 0.f;

    // prologue: batch 0 (4 rows) in flight
    float4 v0 = p4[0 * (C / 4)];
    float4 v1 = p4[1 * (C / 4)];
    float4 v2 = p4[2 * (C / 4)];
    float4 v3 = p4[3 * (C / 4)];
    p4 += 4 * (C / 4);

#pragma unroll 1
    for (int b = 0; b < RPB / 4 - 1; ++b) {
        // issue next batch before consuming current one
        float4 w0 = p4[0 * (C / 4)];
        float4 w1 = p4[1 * (C / 4)];
        float4 w2 = p4[2 * (C / 4)];
        float4 w3 = p4[3 * (C / 4)];
        p4 += 4 * (C / 4);
        __builtin_amdgcn_sched_barrier(0);   // keep the 4 issues above the math

        // consume strictly in load order -> per-register vmcnt, no full drain
        a0 += __expf(v0.x); a1 += __expf(v0.y); a2 += __expf(v0.z); a3 += __expf(v0.w);
        a0 += __expf(v1.x); a1 += __expf(v1.y); a2 += __expf(v1.z); a3 += __expf(v1.w);
        a0 += __expf(v2.x); a1 += __expf(v2.y); a2 += __expf(v2.z); a3 += __expf(v2.w);
        a0 += __expf(v3.x); a1 += __expf(v3.y); a2 += __expf(v3.z); a3 += __expf(v3.w);

        v0 = w0; v1 = w1; v2 = w2; v3 = w3;
    }
    // epilogue: last batch
    a0 += __expf(v0.x); a1 += __expf(v0.y); a2 += __expf(v0.z); a3 += __expf(v0.w);
    a0 += __expf(v1.x); a1 += __expf(v1.y); a2 += __expf(v1.z); a3 += __expf(v1.w);
    a0 += __expf(v2.x); a1 += __expf(v2.y); a2 += __expf(v2.z); a3 += __expf(v2.w);
    a0 += __expf(v3.x); a1 += __expf(v3.y); a2 += __expf(v3.z); a3 += __expf(v3.w);

    reinterpret_cast<float4*>(partial + (size_t)blockIdx.x * C)[tid] =
        make_float4(a0, a1, a2, a3);
}

// ---------------------------------------------------------------------------
// K2: reduce RB partials -> logS. 64 blocks own 16 columns each; a wave reads
// 8 rows x 64 B (full lines); 8 independent accumulator streams. Plain stores
// into owned columns — no atomics. Dispatch boundary publishes logS to K3.
// (Validated R6/R7.)
__global__ __launch_bounds__(256) void colreduce_kernel(
    const float* __restrict__ partial, float* __restrict__ logS, int RB) {
    const int t  = threadIdx.x;
    const int cp = t & 7;          // column-pair slot within the 16-col group
    const int r0 = t >> 3;         // 0..31
    const int c0 = blockIdx.x * 16;
    const int eighth = RB / 8;     // 256 for RB=2048

    const float2* __restrict__ p2 =
        reinterpret_cast<const float2*>(partial) + (c0 >> 1) + cp;

    float2 a[8];
#pragma unroll
    for (int j = 0; j < 8; ++j) a[j] = make_float2(0.f, 0.f);
    for (int r = r0; r < eighth; r += 32) {
#pragma unroll
        for (int j = 0; j < 8; ++j) {
            const float2 v = p2[(size_t)(r + j * eighth) * (C / 2)];
            a[j].x += v.x;
            a[j].y += v.y;
        }
    }
    float2 s;
    s.x = ((a[0].x + a[1].x) + (a[2].x + a[3].x)) + ((a[4].x + a[5].x) + (a[6].x + a[7].x));
    s.y = ((a[0].y + a[1].y) + (a[2].y + a[3].y)) + ((a[4].y + a[5].y) + (a[6].y + a[7].y));
#pragma unroll
    for (int off = 8; off <= 32; off <<= 1) {
        s.x += __shfl_xor(s.x, off, 64);
        s.y += __shfl_xor(s.y, off, 64);
    }
    __shared__ float2 wred[4][8];
    if ((t & 63) < 8) wred[t >> 6][cp] = s;
    __syncthreads();
    if (t < 8) {
        const float vx = wred[0][t].x + wred[1][t].x + wred[2][t].x + wred[3][t].x;
        const float vy = wred[0][t].y + wred[1][t].y + wred[2][t].y + wred[3][t].y;
        logS[c0 + 2 * t]     = log2f(vx);
        logS[c0 + 2 * t + 1] = log2f(vy);
    }
}

// ---------------------------------------------------------------------------
// K3: per-target contribution + finalize. 256 blocks x 256 threads; thread
// handles one target: coalesced tgt read, scattered pred[n,c] dword gather
// (fully parallel), logS gather (4 KB, cache-hot). Block-reduce -> gArr
// (plain store + fence), arrival counter; last block sums gArr[256] and
// finalizes in double. (Validated R7.)
__global__ __launch_bounds__(256) void target_finalize_kernel(
    const int* __restrict__ tgt, const float* __restrict__ pred,
    const float* __restrict__ logS, float* __restrict__ gArr,
    int* __restrict__ counter, float* __restrict__ out) {
    const int t = threadIdx.x;
    const int n = blockIdx.x * 256 + t;
    const int c = tgt[n];
    const float x = pred[((size_t)n << 10) + c];      // C == 1024
    const float LOG2E_F = 1.4426950408889634f;
    float v = LOG2E_F * x - logS[c];
#pragma unroll
    for (int off = 32; off > 0; off >>= 1)
        v += __shfl_down(v, off, 64);
    __shared__ float wsum[4];
    if ((t & 63) == 0) wsum[t >> 6] = v;
    __syncthreads();

    __shared__ int last;
    if (t == 0) {
        gArr[blockIdx.x] = wsum[0] + wsum[1] + wsum[2] + wsum[3];
        __threadfence();           // publish gArr before arrival
        const int old = __hip_atomic_fetch_add(counter, 1, __ATOMIC_ACQ_REL,
                                               __HIP_MEMORY_SCOPE_AGENT);
        last = (old == (int)gridDim.x - 1) ? 1 : 0;
    }
    __syncthreads();
    if (!last) return;

    // tiny tail: 256 floats, full block parallel
    float gl = __hip_atomic_load(&gArr[t], __ATOMIC_RELAXED,
                                 __HIP_MEMORY_SCOPE_AGENT);
#pragma unroll
    for (int off = 32; off > 0; off >>= 1)
        gl += __shfl_down(gl, off, 64);
    __shared__ float r1[4];
    if ((t & 63) == 0) r1[t >> 6] = gl;
    __syncthreads();
    if (t == 0) {
        const double LOG2E = 1.4426950408889634;
        const double SumContrib = (double)(r1[0] + r1[1] + r1[2] + r1[3]);
        const double termA = -LOG2E * (double)C * (1.0 + (double)N * (double)EPS);
        const double total = termA + SumContrib;
        out[0] = (float)(-total / ((double)N * (double)C));
    }
}

extern "C" void kernel_launch(void* const* d_in, const int* in_sizes, int n_in,
                              void* d_out, int out_size, void* d_ws, size_t ws_size,
                              hipStream_t stream) {
    const float* pred = (const float*)d_in[0];
    const int*   tgt  = (const int*)d_in[1];
    float* wsf     = (float*)d_ws;
    float* logS    = wsf;
    int*   counter = (int*)(wsf + 1024);
    float* gArr    = wsf + 1088;               // 256 entries
    float* partial = wsf + 4096;               // 16 KB offset, 16B-aligned
    const size_t base_bytes = 4096 * sizeof(float);

    int RB = 2048;
    while (RB > 512 && base_bytes + (size_t)RB * C * sizeof(float) > ws_size)
        RB >>= 1;

    if (RB >= 2048)
        colsum_kernel<32><<<2048, 256, 0, stream>>>(pred, partial, counter);
    else if (RB == 1024)
        colsum_kernel<64><<<1024, 256, 0, stream>>>(pred, partial, counter);
    else
        colsum_kernel<128><<<512, 256, 0, stream>>>(pred, partial, counter);

    colreduce_kernel<<<64, 256, 0, stream>>>(partial, logS, RB);
    target_finalize_kernel<<<256, 256, 0, stream>>>(tgt, pred, logS, gArr,
                                                    counter, (float*)d_out);
}

// Round 10
// 62.185 us; speedup vs baseline: 1.4014x; 1.0152x over previous
//
#include <hip/hip_runtime.h>
#include <math.h>

// pred [65536, 1024] f32, target [65536] int32
static constexpr int N = 65536;
static constexpr int C = 1024;
static constexpr float EPS = 1e-9f;

// Math (validated absmax==0.0 in R4..R9):
//   total = termA + sum_t (log2e*x_t - log2(S[c_t]))
//   termA = -log2e * C * (1 + N*EPS)       (analytic: softmax cols sum to 1)
//   loss  = -total / (N*C)
//
// ws float layout (no pre-zeroing dispatch; no atomic accumulators):
//   [0..1023]   logS[C]        written by K2 (plain owned-column stores)
//   [1024]      counter        zeroed by K1 block 0; K3 arrival counter
//   [1088..1343] gArr[256]     per-block partial contributions (K3)
//   [4096..]    partial[GRID][C] per-block column partials (K1)

// ---------------------------------------------------------------------------
// K1: streaming column partials of exp — GRID-COOPERATIVE SWEEP layout.
// R9 lesson: depth-8/16w and depth-4/32w both plateau at ~4.9 TB/s -> the
// limit is the memory-access SHAPE, not latency hiding. Old layout gave each
// block a private 128 KB segment: 2048 scattered streams across 256 MB at
// every instant (DRAM row churn). New layout: iteration i, block b reads the
// 4 contiguous rows 4*(i*GRID+b).. so each block-iteration is 16 KB
// contiguous and the WHOLE GRID's iteration i covers one contiguous 32 MB
// window sweeping the matrix — the fill/copy-kernel shape that hits 6.3-7
// TB/s. Column partials are row-subset-invariant.
// Depth-4 software pipeline, consume-in-load-order (per-register vmcnt).
template <int GRID>
__global__ __launch_bounds__(256, 8) void colsum_kernel(
    const float* __restrict__ pred, float* __restrict__ partial,
    int* __restrict__ counter) {
    const int tid = threadIdx.x;                   // 0..255
    if (blockIdx.x == 0 && tid == 0) *counter = 0; // for K3's arrival counter

    constexpr int ITERS = N / (4 * GRID);          // 8 for GRID=2048
    const float4* __restrict__ base =
        reinterpret_cast<const float4*>(pred) + tid;

    float a0 = 0.f, a1 = 0.f, a2 = 0.f, a3 = 0.f;

    // prologue: group 0 = rows 4*blockIdx.x .. +3 (16 KB contiguous)
    const float4* p = base + (size_t)blockIdx.x * 4 * (C / 4);
    float4 v0 = p[0 * (C / 4)];
    float4 v1 = p[1 * (C / 4)];
    float4 v2 = p[2 * (C / 4)];
    float4 v3 = p[3 * (C / 4)];

#pragma unroll 1
    for (int i = 1; i < ITERS; ++i) {
        // next group: 32 MB further down — the grid sweeps together
        const float4* pn = base + ((size_t)i * GRID + blockIdx.x) * 4 * (C / 4);
        float4 w0 = pn[0 * (C / 4)];
        float4 w1 = pn[1 * (C / 4)];
        float4 w2 = pn[2 * (C / 4)];
        float4 w3 = pn[3 * (C / 4)];
        __builtin_amdgcn_sched_barrier(0);   // keep the 4 issues above the math

        // consume strictly in load order -> per-register vmcnt, no full drain
        a0 += __expf(v0.x); a1 += __expf(v0.y); a2 += __expf(v0.z); a3 += __expf(v0.w);
        a0 += __expf(v1.x); a1 += __expf(v1.y); a2 += __expf(v1.z); a3 += __expf(v1.w);
        a0 += __expf(v2.x); a1 += __expf(v2.y); a2 += __expf(v2.z); a3 += __expf(v2.w);
        a0 += __expf(v3.x); a1 += __expf(v3.y); a2 += __expf(v3.z); a3 += __expf(v3.w);

        v0 = w0; v1 = w1; v2 = w2; v3 = w3;
    }
    // epilogue: last group
    a0 += __expf(v0.x); a1 += __expf(v0.y); a2 += __expf(v0.z); a3 += __expf(v0.w);
    a0 += __expf(v1.x); a1 += __expf(v1.y); a2 += __expf(v1.z); a3 += __expf(v1.w);
    a0 += __expf(v2.x); a1 += __expf(v2.y); a2 += __expf(v2.z); a3 += __expf(v2.w);
    a0 += __expf(v3.x); a1 += __expf(v3.y); a2 += __expf(v3.z); a3 += __expf(v3.w);

    reinterpret_cast<float4*>(partial + (size_t)blockIdx.x * C)[tid] =
        make_float4(a0, a1, a2, a3);
}

// ---------------------------------------------------------------------------
// K2: reduce RB partials -> logS. 64 blocks own 16 columns each; a wave reads
// 8 rows x 64 B (full lines); 8 independent accumulator streams. Plain stores
// into owned columns — no atomics. Dispatch boundary publishes logS to K3.
// (Validated R6/R7/R9.)
__global__ __launch_bounds__(256) void colreduce_kernel(
    const float* __restrict__ partial, float* __restrict__ logS, int RB) {
    const int t  = threadIdx.x;
    const int cp = t & 7;          // column-pair slot within the 16-col group
    const int r0 = t >> 3;         // 0..31
    const int c0 = blockIdx.x * 16;
    const int eighth = RB / 8;     // 256 for RB=2048

    const float2* __restrict__ p2 =
        reinterpret_cast<const float2*>(partial) + (c0 >> 1) + cp;

    float2 a[8];
#pragma unroll
    for (int j = 0; j < 8; ++j) a[j] = make_float2(0.f, 0.f);
    for (int r = r0; r < eighth; r += 32) {
#pragma unroll
        for (int j = 0; j < 8; ++j) {
            const float2 v = p2[(size_t)(r + j * eighth) * (C / 2)];
            a[j].x += v.x;
            a[j].y += v.y;
        }
    }
    float2 s;
    s.x = ((a[0].x + a[1].x) + (a[2].x + a[3].x)) + ((a[4].x + a[5].x) + (a[6].x + a[7].x));
    s.y = ((a[0].y + a[1].y) + (a[2].y + a[3].y)) + ((a[4].y + a[5].y) + (a[6].y + a[7].y));
#pragma unroll
    for (int off = 8; off <= 32; off <<= 1) {
        s.x += __shfl_xor(s.x, off, 64);
        s.y += __shfl_xor(s.y, off, 64);
    }
    __shared__ float2 wred[4][8];
    if ((t & 63) < 8) wred[t >> 6][cp] = s;
    __syncthreads();
    if (t < 8) {
        const float vx = wred[0][t].x + wred[1][t].x + wred[2][t].x + wred[3][t].x;
        const float vy = wred[0][t].y + wred[1][t].y + wred[2][t].y + wred[3][t].y;
        logS[c0 + 2 * t]     = log2f(vx);
        logS[c0 + 2 * t + 1] = log2f(vy);
    }
}

// ---------------------------------------------------------------------------
// K3: per-target contribution + finalize. 256 blocks x 256 threads; thread
// handles one target: coalesced tgt read, scattered pred[n,c] dword gather
// (fully parallel), logS gather (4 KB, cache-hot). Block-reduce -> gArr
// (plain store + fence), arrival counter; last block sums gArr[256] and
// finalizes in double. (Validated R7/R9.)
__global__ __launch_bounds__(256) void target_finalize_kernel(
    const int* __restrict__ tgt, const float* __restrict__ pred,
    const float* __restrict__ logS, float* __restrict__ gArr,
    int* __restrict__ counter, float* __restrict__ out) {
    const int t = threadIdx.x;
    const int n = blockIdx.x * 256 + t;
    const int c = tgt[n];
    const float x = pred[((size_t)n << 10) + c];      // C == 1024
    const float LOG2E_F = 1.4426950408889634f;
    float v = LOG2E_F * x - logS[c];
#pragma unroll
    for (int off = 32; off > 0; off >>= 1)
        v += __shfl_down(v, off, 64);
    __shared__ float wsum[4];
    if ((t & 63) == 0) wsum[t >> 6] = v;
    __syncthreads();

    __shared__ int last;
    if (t == 0) {
        gArr[blockIdx.x] = wsum[0] + wsum[1] + wsum[2] + wsum[3];
        __threadfence();           // publish gArr before arrival
        const int old = __hip_atomic_fetch_add(counter, 1, __ATOMIC_ACQ_REL,
                                               __HIP_MEMORY_SCOPE_AGENT);
        last = (old == (int)gridDim.x - 1) ? 1 : 0;
    }
    __syncthreads();
    if (!last) return;

    // tiny tail: 256 floats, full block parallel
    float gl = __hip_atomic_load(&gArr[t], __ATOMIC_RELAXED,
                                 __HIP_MEMORY_SCOPE_AGENT);
#pragma unroll
    for (int off = 32; off > 0; off >>= 1)
        gl += __shfl_down(gl, off, 64);
    __shared__ float r1[4];
    if ((t & 63) == 0) r1[t >> 6] = gl;
    __syncthreads();
    if (t == 0) {
        const double LOG2E = 1.4426950408889634;
        const double SumContrib = (double)(r1[0] + r1[1] + r1[2] + r1[3]);
        const double termA = -LOG2E * (double)C * (1.0 + (double)N * (double)EPS);
        const double total = termA + SumContrib;
        out[0] = (float)(-total / ((double)N * (double)C));
    }
}

extern "C" void kernel_launch(void* const* d_in, const int* in_sizes, int n_in,
                              void* d_out, int out_size, void* d_ws, size_t ws_size,
                              hipStream_t stream) {
    const float* pred = (const float*)d_in[0];
    const int*   tgt  = (const int*)d_in[1];
    float* wsf     = (float*)d_ws;
    float* logS    = wsf;
    int*   counter = (int*)(wsf + 1024);
    float* gArr    = wsf + 1088;               // 256 entries
    float* partial = wsf + 4096;               // 16 KB offset, 16B-aligned
    const size_t base_bytes = 4096 * sizeof(float);

    int RB = 2048;
    while (RB > 512 && base_bytes + (size_t)RB * C * sizeof(float) > ws_size)
        RB >>= 1;

    if (RB >= 2048)
        colsum_kernel<2048><<<2048, 256, 0, stream>>>(pred, partial, counter);
    else if (RB == 1024)
        colsum_kernel<1024><<<1024, 256, 0, stream>>>(pred, partial, counter);
    else
        colsum_kernel<512><<<512, 256, 0, stream>>>(pred, partial, counter);

    colreduce_kernel<<<64, 256, 0, stream>>>(partial, logS, RB);
    target_finalize_kernel<<<256, 256, 0, stream>>>(tgt, pred, logS, gArr,
                                                    counter, (float*)d_out);
}